// Round 4
// baseline (112.010 us; speedup 1.0000x reference)
//
#include <hip/hip_runtime.h>
#include <hip/hip_bf16.h>

// MXEPLoss analytic + MFMA-bf16 dots GEMM, barrier-free K-loop.
// Inputs: xq [Nq,D] f32, yq [Nq] i32, xs [Ns,D] f32, ys [Ns] i32, pos [Nq] i32
// Shapes fixed by bench: Nq=Ns=4096, D=1024, K=128 classes. Output: scalar f32.
//
// R4: A- and B-fragments are loaded DIRECTLY from global into registers in
// MFMA fragment layout (lane l16 = row, quad*8 = k-offset; 16 B aligned) --
// no LDS staging, no double buffer, no per-iter barrier. q2/own fold into the
// A-frag loads (quad partials reduced via shfl_xor 16/32). Only the epilogue
// dots-exchange uses LDS (one barrier). Main becomes HBM-bound on its 32 MB
// irreducible xq + xs[pos] read.

#define KCLS 128
#define QB 16

typedef __attribute__((ext_vector_type(8))) short short8;
typedef __attribute__((ext_vector_type(4))) float f32x4;

__device__ __forceinline__ short f2bs(float f) {
    __hip_bfloat16 h = __float2bfloat16(f);
    short s; __builtin_memcpy(&s, &h, 2); return s;
}

// ---------------- class stats: 512 blocks = 128 classes x 4 dim-quarters ----
__global__ __launch_bounds__(256) void class_stats2(
    const float* __restrict__ xs, const int* __restrict__ ys,
    int Ns, int D,
    short* __restrict__ protoC,      // bf16 [KCLS][D] class-major
    float* __restrict__ S2part,      // [KCLS][4]
    float* __restrict__ mu2part,     // [KCLS][4]
    int* __restrict__ cntArr, float* __restrict__ out)
{
    const int c = blockIdx.x >> 2;
    const int quarter = blockIdx.x & 3;
    const int t = threadIdx.x;
    const int dim = quarter * 256 + t;          // D == 1024 assumed
    if (blockIdx.x == 0 && t == 0) out[0] = 0.f;   // main runs after us on the stream
    __shared__ int list[4096];
    __shared__ int lcnt;
    __shared__ float red[256];
    if (t == 0) lcnt = 0;
    __syncthreads();
    for (int s = t; s < Ns; s += 256) {
        if (ys[s] == c) list[atomicAdd(&lcnt, 1)] = s;
    }
    __syncthreads();
    const int n = lcnt;
    float a = 0.f, s2p = 0.f;
    int r = 0;
    for (; r + 4 <= n; r += 4) {                // 4-deep MLP on load latency
        const float x0 = xs[(size_t)list[r]     * D + dim];
        const float x1 = xs[(size_t)list[r + 1] * D + dim];
        const float x2 = xs[(size_t)list[r + 2] * D + dim];
        const float x3 = xs[(size_t)list[r + 3] * D + dim];
        a += x0 + x1 + x2 + x3;
        s2p += x0 * x0 + x1 * x1 + x2 * x2 + x3 * x3;
    }
    for (; r < n; ++r) {
        const float x = xs[(size_t)list[r] * D + dim];
        a += x; s2p += x * x;
    }
    const float inv = 1.0f / fmaxf((float)n, 0.1f);
    protoC[(size_t)c * D + dim] = f2bs(a * inv);

    red[t] = a * a; __syncthreads();
    for (int o = 128; o > 0; o >>= 1) { if (t < o) red[t] += red[t + o]; __syncthreads(); }
    if (t == 0) mu2part[c * 4 + quarter] = red[0];
    __syncthreads();
    red[t] = s2p; __syncthreads();
    for (int o = 128; o > 0; o >>= 1) { if (t < o) red[t] += red[t + o]; __syncthreads(); }
    if (t == 0) {
        S2part[c * 4 + quarter] = red[0];
        if (quarter == 0) cntArr[c] = n;
    }
}

// ---------------- main: barrier-free MFMA dots + fused own + epilogue ------
// 256 blocks x 256 threads. Block = 16 queries x all 128 classes.
// Wave w computes classes [32w, 32w+32) as two 16x16x32 MFMA accumulators.
__global__ __launch_bounds__(256) void main_mfma(
    const float* __restrict__ xq, const int* __restrict__ yq,
    const int* __restrict__ ys, const int* __restrict__ posA,
    const short* __restrict__ protoC,   // bf16 [KCLS][D]
    const float* __restrict__ S2part, const float* __restrict__ mu2part,
    const int* __restrict__ cntArr, const float* __restrict__ xs,
    int Nq, int D, float invNq, float* __restrict__ out)
{
    const int t    = threadIdx.x;
    const int lane = t & 63;
    const int wave = t >> 6;
    const int quad = lane >> 4;
    const int l16  = lane & 15;
    const int qb0  = blockIdx.x * QB;

    __shared__ float dotsS[QB * 132];   // stride 132: conflict-free C-scatter
    __shared__ float pn2S[KCLS];
    __shared__ float mu2S[KCLS];
    __shared__ float S2S[KCLS];
    __shared__ int   cntIS[KCLS];
    __shared__ float q2S[QB], ownS[QB], diffS[QB];

    if (t < KCLS) {
        const int n = cntArr[t];
        const float cl = fmaxf((float)n, 0.1f);
        const float m2 = mu2part[t * 4] + mu2part[t * 4 + 1]
                       + mu2part[t * 4 + 2] + mu2part[t * 4 + 3];
        cntIS[t] = n;
        mu2S[t]  = m2;
        pn2S[t]  = m2 / (cl * cl);
        S2S[t]   = S2part[t * 4] + S2part[t * 4 + 1]
                 + S2part[t * 4 + 2] + S2part[t * 4 + 3];
    }

    // Fragment-layout global pointers (16 B aligned: quad*8 elems).
    const float* aRow = xq + (size_t)(qb0 + l16) * D + quad * 8;
    const float* sRow = xs + (size_t)posA[qb0 + l16] * D + quad * 8;
    const short* b0p  = protoC + (size_t)(32 * wave + l16) * D + quad * 8;
    const short* b1p  = b0p + (size_t)16 * D;

    f32x4 acc0 = {0.f, 0.f, 0.f, 0.f};
    f32x4 acc1 = {0.f, 0.f, 0.f, 0.f};
    float q2p = 0.f, ownp = 0.f;

    #pragma unroll 4
    for (int kc = 0; kc < D; kc += 32) {
        const float4 a0 = *(const float4*)(aRow + kc);
        const float4 a1 = *(const float4*)(aRow + kc + 4);
        const float4 s0 = *(const float4*)(sRow + kc);
        const float4 s1 = *(const float4*)(sRow + kc + 4);
        const short8 b0 = *(const short8*)(b0p + kc);
        const short8 b1 = *(const short8*)(b1p + kc);

        q2p += a0.x * a0.x + a0.y * a0.y + a0.z * a0.z + a0.w * a0.w
             + a1.x * a1.x + a1.y * a1.y + a1.z * a1.z + a1.w * a1.w;
        {
            const float d0 = a0.x - s0.x, d1 = a0.y - s0.y;
            const float d2 = a0.z - s0.z, d3 = a0.w - s0.w;
            const float d4 = a1.x - s1.x, d5 = a1.y - s1.y;
            const float d6 = a1.z - s1.z, d7 = a1.w - s1.w;
            ownp += d0 * d0 + d1 * d1 + d2 * d2 + d3 * d3
                  + d4 * d4 + d5 * d5 + d6 * d6 + d7 * d7;
        }

        short8 a16;
        a16[0] = f2bs(a0.x); a16[1] = f2bs(a0.y);
        a16[2] = f2bs(a0.z); a16[3] = f2bs(a0.w);
        a16[4] = f2bs(a1.x); a16[5] = f2bs(a1.y);
        a16[6] = f2bs(a1.z); a16[7] = f2bs(a1.w);

        acc0 = __builtin_amdgcn_mfma_f32_16x16x32_bf16(a16, b0, acc0, 0, 0, 0);
        acc1 = __builtin_amdgcn_mfma_f32_16x16x32_bf16(a16, b1, acc1, 0, 0, 0);
    }

    // q2/own: quad partials for query l16 -> full sum in every lane
    q2p  += __shfl_xor(q2p, 16);  q2p  += __shfl_xor(q2p, 32);
    ownp += __shfl_xor(ownp, 16); ownp += __shfl_xor(ownp, 32);
    if (t < 16) { q2S[t] = q2p; ownS[t] = ownp; }   // wave 0, lanes 0..15

    // scatter MFMA C-layout (col=lane&15, row=quad*4+reg) into dotsS[q][c]
    {
        const int cb = 32 * wave;
        #pragma unroll
        for (int r = 0; r < 4; ++r) {
            dotsS[(quad * 4 + r) * 132 + cb      + l16] = acc0[r];
            dotsS[(quad * 4 + r) * 132 + cb + 16 + l16] = acc1[r];
        }
    }
    __syncthreads();

    // ---------------- epilogue (verified logic from R1..R3) ----------------
    const int qg = t >> 4;
    const int cg = t & 15;
    const int qi = qb0 + qg;
    const float q2 = q2S[qg];

    const int p  = posA[qi];
    const int ci = ys[p];
    const int cnt_i = cntIS[ci];
    const float cnt_ci  = (float)cnt_i;
    const float clip_ci = fmaxf(cnt_ci, 0.1f);
    const float dotmu   = dotsS[qg * 132 + ci] * clip_ci;   // xq . mus[ci]
    const float Ccl     = fmaxf(cnt_ci - 1.0f, 0.1f);
    const float dqM     = dotmu - q2;
    const float M2      = mu2S[ci] - 2.f * dotmu + q2;
    const float dpos2   = q2 - 2.f * dqM / Ccl + M2 / (Ccl * Ccl);
    const float d_pos   = sqrtf(fmaxf(dpos2, 0.f) + 1e-12f);

    float ld[8];
    float m = -3.0e38f;
    #pragma unroll
    for (int j = 0; j < 8; ++j) {
        const int c = cg * 8 + j;
        const float dot = dotsS[qg * 132 + c];
        const float sq_ = fmaxf(q2 + pn2S[c] - 2.f * dot, 0.f) + 1e-12f;
        float v = -sqrtf(sq_);
        if (c == ci) v = -d_pos;
        ld[j] = v;
        m = fmaxf(m, v);
    }
    #pragma unroll
    for (int o = 1; o < 16; o <<= 1) m = fmaxf(m, __shfl_xor(m, o));
    float se = 0.f;
    #pragma unroll
    for (int j = 0; j < 8; ++j) se += expf(ld[j] - m);
    #pragma unroll
    for (int o = 1; o < 16; o <<= 1) se += __shfl_xor(se, o);
    const float lse = m + logf(se);

    if (cg == 0) {
        const int cl = yq[qi];
        const int cntl_i = cntIS[cl];
        const float cntl = (float)cntl_i;
        const float dotmu_l = dotsS[qg * 132 + cl] * fmaxf(cntl, 0.1f); // xq . mus[cl]
        const float sum_sqd = cntl * q2 - 2.f * dotmu_l + S2S[cl];
        const bool m_own = (cl == ci);
        const bool idxq  = (cntl_i > 1);
        const float numer = -0.5f * (sum_sqd - (m_own ? ownS[qg] : 0.f));
        const float denom = cntl - ((m_own && idxq) ? 1.f : 0.f);
        diffS[qg] = lse - numer / denom;
    }
    __syncthreads();
    if (t == 0) {
        float ssum = 0.f;
        #pragma unroll
        for (int q = 0; q < QB; ++q) ssum += diffS[q];
        atomicAdd(out, ssum * invNq);
    }
}

extern "C" void kernel_launch(void* const* d_in, const int* in_sizes, int n_in,
                              void* d_out, int out_size, void* d_ws, size_t ws_size,
                              hipStream_t stream) {
    const float* xq  = (const float*)d_in[0];
    const int*   yq  = (const int*)d_in[1];
    const float* xs  = (const float*)d_in[2];
    const int*   ys  = (const int*)d_in[3];
    const int*   pos = (const int*)d_in[4];

    const int Nq = in_sizes[1];
    const int Ns = in_sizes[3];
    const int D  = in_sizes[0] / Nq;   // 1024

    char* w = (char*)d_ws;
    short* protoC  = (short*)w;  w += (size_t)KCLS * D * sizeof(short);  // bf16 [K][D]
    float* mu2part = (float*)w;  w += (size_t)KCLS * 4 * sizeof(float);
    float* S2part  = (float*)w;  w += (size_t)KCLS * 4 * sizeof(float);
    int*   cntA    = (int*)w;    w += KCLS * sizeof(int);

    float* out = (float*)d_out;

    class_stats2<<<KCLS * 4, 256, 0, stream>>>(xs, ys, Ns, D, protoC,
                                               S2part, mu2part, cntA, out);
    main_mfma<<<Nq / QB, 256, 0, stream>>>(xq, yq, ys, pos, protoC, S2part, mu2part,
                                           cntA, xs, Nq, D, 1.0f / (float)Nq, out);
}

// Round 5
// 101.337 us; speedup vs baseline: 1.1053x; 1.1053x over previous
//
#include <hip/hip_runtime.h>
#include <hip/hip_bf16.h>

// MXEPLoss analytic + MFMA-bf16 dots GEMM, software-pipelined (prefetch-2).
// Inputs: xq [Nq,D] f32, yq [Nq] i32, xs [Ns,D] f32, ys [Ns] i32, pos [Nq] i32
// Shapes fixed by bench: Nq=Ns=4096, D=1024, K=128 classes. Output: scalar f32.
//
// R5 = R3 structure (LDS-staged, coalesced, one barrier/iter) + prefetch
// distance 2 (two register sets; loads for iter k+2 issued at iter k so
// ~1100 cyc in flight >= HBM latency; VGPRs are free at 1 block/CU) +
// shuffle-reduced class_stats with 8-deep load pipelining.

#define KCLS 128
#define QB 16
#define BK 64

typedef __attribute__((ext_vector_type(8))) short short8;
typedef __attribute__((ext_vector_type(4))) float f32x4;

__device__ __forceinline__ short f2bs(float f) {
    __hip_bfloat16 h = __float2bfloat16(f);
    short s; __builtin_memcpy(&s, &h, 2); return s;
}

// ---------------- class stats: 512 blocks = 128 classes x 4 dim-quarters ----
__global__ __launch_bounds__(256) void class_stats2(
    const float* __restrict__ xs, const int* __restrict__ ys,
    int Ns, int D,
    short* __restrict__ protoC,      // bf16 [KCLS][D] class-major
    float* __restrict__ S2part,      // [KCLS][4]
    float* __restrict__ mu2part,     // [KCLS][4]
    int* __restrict__ cntArr, float* __restrict__ out)
{
    const int c = blockIdx.x >> 2;
    const int quarter = blockIdx.x & 3;
    const int t = threadIdx.x;
    const int dim = quarter * 256 + t;          // D == 1024 assumed
    if (blockIdx.x == 0 && t == 0) out[0] = 0.f;   // main runs after us on the stream
    __shared__ int list[4096];
    __shared__ int lcnt;
    __shared__ float redm[4], reds[4];
    if (t == 0) lcnt = 0;
    __syncthreads();
    for (int s = t; s < Ns; s += 256) {
        if (ys[s] == c) list[atomicAdd(&lcnt, 1)] = s;
    }
    __syncthreads();
    const int n = lcnt;
    float a = 0.f, s2p = 0.f;
    int r = 0;
    for (; r + 8 <= n; r += 8) {                // 8-deep MLP on load latency
        float x0 = xs[(size_t)list[r]     * D + dim];
        float x1 = xs[(size_t)list[r + 1] * D + dim];
        float x2 = xs[(size_t)list[r + 2] * D + dim];
        float x3 = xs[(size_t)list[r + 3] * D + dim];
        float x4 = xs[(size_t)list[r + 4] * D + dim];
        float x5 = xs[(size_t)list[r + 5] * D + dim];
        float x6 = xs[(size_t)list[r + 6] * D + dim];
        float x7 = xs[(size_t)list[r + 7] * D + dim];
        a += ((x0 + x1) + (x2 + x3)) + ((x4 + x5) + (x6 + x7));
        s2p += x0 * x0 + x1 * x1 + x2 * x2 + x3 * x3
             + x4 * x4 + x5 * x5 + x6 * x6 + x7 * x7;
    }
    for (; r < n; ++r) {
        const float x = xs[(size_t)list[r] * D + dim];
        a += x; s2p += x * x;
    }
    const float inv = 1.0f / fmaxf((float)n, 0.1f);
    protoC[(size_t)c * D + dim] = f2bs(a * inv);

    float v1 = a * a, v2 = s2p;
    #pragma unroll
    for (int o = 1; o < 64; o <<= 1) {
        v1 += __shfl_xor(v1, o);
        v2 += __shfl_xor(v2, o);
    }
    if ((t & 63) == 0) { redm[t >> 6] = v1; reds[t >> 6] = v2; }
    __syncthreads();
    if (t == 0) {
        mu2part[c * 4 + quarter] = (redm[0] + redm[1]) + (redm[2] + redm[3]);
        S2part[c * 4 + quarter]  = (reds[0] + reds[1]) + (reds[2] + reds[3]);
        if (quarter == 0) cntArr[c] = n;
    }
}

// ---------------- main: pipelined MFMA dots + fused own + epilogue ----------
// 256 blocks x 256 threads. Block = 16 queries x all 128 classes.
// Wave w computes classes [32w, 32w+32) as two 16x16x32 MFMA accumulators.
__global__ __launch_bounds__(256) void main_mfma(
    const float* __restrict__ xq, const int* __restrict__ yq,
    const int* __restrict__ ys, const int* __restrict__ posA,
    const short* __restrict__ protoC,   // bf16 [KCLS][D]
    const float* __restrict__ S2part, const float* __restrict__ mu2part,
    const int* __restrict__ cntArr, const float* __restrict__ xs,
    int Nq, int D, float invNq, float* __restrict__ out)
{
    const int t    = threadIdx.x;
    const int lane = t & 63;
    const int wave = t >> 6;
    const int quad = lane >> 4;
    const int l16  = lane & 15;
    const int qb0  = blockIdx.x * QB;

    // padded LDS (stride 72 shorts = 144 B: even-bank b128 frag access)
    __shared__ short Asb[2][QB * 72];
    __shared__ short Bsb[2][KCLS * 72];
    __shared__ float dotsS[QB * 132];   // stride 132: conflict-free C-scatter
    __shared__ float pn2S[KCLS];
    __shared__ float mu2S[KCLS];
    __shared__ float S2S[KCLS];
    __shared__ int   cntIS[KCLS];
    __shared__ float q2S[QB], ownS[QB], diffS[QB];

    if (t < KCLS) {
        const int n = cntArr[t];
        const float cl = fmaxf((float)n, 0.1f);
        const float m2 = mu2part[t * 4] + mu2part[t * 4 + 1]
                       + mu2part[t * 4 + 2] + mu2part[t * 4 + 3];
        cntIS[t] = n;
        mu2S[t]  = m2;
        pn2S[t]  = m2 / (cl * cl);
        S2S[t]   = S2part[t * 4] + S2part[t * 4 + 1]
                 + S2part[t * 4 + 2] + S2part[t * 4 + 3];
    }

    // staging roles
    const int sq = t >> 4;            // query row 0..15 (A staging + epilogue qg)
    const int sk = (t & 15) * 4;      // k offset (floats) within chunk
    const float* aRow = xq + (size_t)(qb0 + sq) * D;
    const float* sRow = xs + (size_t)posA[qb0 + sq] * D;
    const int bc  = t >> 3;           // B staging base row 0..31
    const int bk8 = (t & 7) * 8;      // B col offset (shorts)
    const short* bBase = protoC + (size_t)bc * D + bk8;
    const size_t bStride = (size_t)32 * D;

    f32x4 acc0 = {0.f, 0.f, 0.f, 0.f};
    f32x4 acc1 = {0.f, 0.f, 0.f, 0.f};
    float q2p = 0.f, ownp = 0.f;

    const int aro = l16 * 72 + quad * 8;             // A frag read offset
    const int br0 = (32 * wave      + l16) * 72 + quad * 8;
    const int br1 = (32 * wave + 16 + l16) * 72 + quad * 8;

    // prologue: loads for chunks 0 (set0) and 1 (set1)
    float4 av0 = *(const float4*)(aRow + sk);
    float4 sv0 = *(const float4*)(sRow + sk);
    int4 b00 = *(const int4*)(bBase);
    int4 b01 = *(const int4*)(bBase + bStride);
    int4 b02 = *(const int4*)(bBase + 2 * bStride);
    int4 b03 = *(const int4*)(bBase + 3 * bStride);
    float4 av1 = *(const float4*)(aRow + BK + sk);
    float4 sv1 = *(const float4*)(sRow + BK + sk);
    int4 b10 = *(const int4*)(bBase + BK);
    int4 b11 = *(const int4*)(bBase + bStride + BK);
    int4 b12 = *(const int4*)(bBase + 2 * bStride + BK);
    int4 b13 = *(const int4*)(bBase + 3 * bStride + BK);

#define KSTEP(AV, SV, B0, B1, B2, B3, BUF, KBN, VALID)                        \
    {                                                                          \
        short* Ab = Asb[BUF];                                                  \
        short* Bb = Bsb[BUF];                                                  \
        short4 a16;                                                            \
        a16.x = f2bs(AV.x); a16.y = f2bs(AV.y);                                \
        a16.z = f2bs(AV.z); a16.w = f2bs(AV.w);                                \
        *(short4*)(&Ab[sq * 72 + sk]) = a16;                                   \
        *(int4*)(&Bb[bc * 72 + bk8]) = B0;                                     \
        *(int4*)(&Bb[(bc + 32) * 72 + bk8]) = B1;                              \
        *(int4*)(&Bb[(bc + 64) * 72 + bk8]) = B2;                              \
        *(int4*)(&Bb[(bc + 96) * 72 + bk8]) = B3;                              \
        q2p += AV.x * AV.x + AV.y * AV.y + AV.z * AV.z + AV.w * AV.w;          \
        {                                                                      \
            const float dx = AV.x - SV.x, dy = AV.y - SV.y;                    \
            const float dz = AV.z - SV.z, dw = AV.w - SV.w;                    \
            ownp += dx * dx + dy * dy + dz * dz + dw * dw;                     \
        }                                                                      \
        __syncthreads();                                                       \
        if (VALID) {   /* prefetch distance 2: flies across 2 MFMA phases */   \
            AV = *(const float4*)(aRow + (KBN) + sk);                          \
            SV = *(const float4*)(sRow + (KBN) + sk);                          \
            B0 = *(const int4*)(bBase + (KBN));                                \
            B1 = *(const int4*)(bBase + bStride + (KBN));                      \
            B2 = *(const int4*)(bBase + 2 * bStride + (KBN));                  \
            B3 = *(const int4*)(bBase + 3 * bStride + (KBN));                  \
        }                                                                      \
        _Pragma("unroll")                                                      \
        for (int ks = 0; ks < BK; ks += 32) {                                  \
            const short8 a  = *(const short8*)(&Ab[aro + ks]);                 \
            const short8 bf0 = *(const short8*)(&Bb[br0 + ks]);                \
            const short8 bf1 = *(const short8*)(&Bb[br1 + ks]);                \
            acc0 = __builtin_amdgcn_mfma_f32_16x16x32_bf16(a, bf0, acc0, 0, 0, 0); \
            acc1 = __builtin_amdgcn_mfma_f32_16x16x32_bf16(a, bf1, acc1, 0, 0, 0); \
        }                                                                      \
    }

    for (int it = 0; it < 16; it += 2) {
        KSTEP(av0, sv0, b00, b01, b02, b03, 0, (it + 2) * BK, (it + 2) < 16)
        KSTEP(av1, sv1, b10, b11, b12, b13, 1, (it + 3) * BK, (it + 3) < 16)
    }
#undef KSTEP

    // q2/own: 16 partials per query live in lanes (t&15) of the same wave
    #pragma unroll
    for (int o = 1; o < 16; o <<= 1) {
        q2p  += __shfl_xor(q2p, o);
        ownp += __shfl_xor(ownp, o);
    }
    if ((t & 15) == 0) { q2S[sq] = q2p; ownS[sq] = ownp; }

    // scatter MFMA C-layout (col=lane&15, row=quad*4+reg) into dotsS[q][c]
    {
        const int cb = 32 * wave;
        #pragma unroll
        for (int r = 0; r < 4; ++r) {
            dotsS[(quad * 4 + r) * 132 + cb      + l16] = acc0[r];
            dotsS[(quad * 4 + r) * 132 + cb + 16 + l16] = acc1[r];
        }
    }
    __syncthreads();

    // ---------------- epilogue (verified logic from R1..R3) ----------------
    const int qg = t >> 4;
    const int cg = t & 15;
    const int qi = qb0 + qg;
    const float q2 = q2S[qg];

    const int p  = posA[qi];
    const int ci = ys[p];
    const int cnt_i = cntIS[ci];
    const float cnt_ci  = (float)cnt_i;
    const float clip_ci = fmaxf(cnt_ci, 0.1f);
    const float dotmu   = dotsS[qg * 132 + ci] * clip_ci;   // xq . mus[ci]
    const float Ccl     = fmaxf(cnt_ci - 1.0f, 0.1f);
    const float dqM     = dotmu - q2;
    const float M2      = mu2S[ci] - 2.f * dotmu + q2;
    const float dpos2   = q2 - 2.f * dqM / Ccl + M2 / (Ccl * Ccl);
    const float d_pos   = sqrtf(fmaxf(dpos2, 0.f) + 1e-12f);

    float ld[8];
    float m = -3.0e38f;
    #pragma unroll
    for (int j = 0; j < 8; ++j) {
        const int c = cg * 8 + j;
        const float dot = dotsS[qg * 132 + c];
        const float sq_ = fmaxf(q2 + pn2S[c] - 2.f * dot, 0.f) + 1e-12f;
        float v = -sqrtf(sq_);
        if (c == ci) v = -d_pos;
        ld[j] = v;
        m = fmaxf(m, v);
    }
    #pragma unroll
    for (int o = 1; o < 16; o <<= 1) m = fmaxf(m, __shfl_xor(m, o));
    float se = 0.f;
    #pragma unroll
    for (int j = 0; j < 8; ++j) se += expf(ld[j] - m);
    #pragma unroll
    for (int o = 1; o < 16; o <<= 1) se += __shfl_xor(se, o);
    const float lse = m + logf(se);

    if (cg == 0) {
        const int cl = yq[qi];
        const int cntl_i = cntIS[cl];
        const float cntl = (float)cntl_i;
        const float dotmu_l = dotsS[qg * 132 + cl] * fmaxf(cntl, 0.1f); // xq . mus[cl]
        const float sum_sqd = cntl * q2 - 2.f * dotmu_l + S2S[cl];
        const bool m_own = (cl == ci);
        const bool idxq  = (cntl_i > 1);
        const float numer = -0.5f * (sum_sqd - (m_own ? ownS[qg] : 0.f));
        const float denom = cntl - ((m_own && idxq) ? 1.f : 0.f);
        diffS[qg] = lse - numer / denom;
    }
    __syncthreads();
    if (t == 0) {
        float ssum = 0.f;
        #pragma unroll
        for (int q = 0; q < QB; ++q) ssum += diffS[q];
        atomicAdd(out, ssum * invNq);
    }
}

extern "C" void kernel_launch(void* const* d_in, const int* in_sizes, int n_in,
                              void* d_out, int out_size, void* d_ws, size_t ws_size,
                              hipStream_t stream) {
    const float* xq  = (const float*)d_in[0];
    const int*   yq  = (const int*)d_in[1];
    const float* xs  = (const float*)d_in[2];
    const int*   ys  = (const int*)d_in[3];
    const int*   pos = (const int*)d_in[4];

    const int Nq = in_sizes[1];
    const int Ns = in_sizes[3];
    const int D  = in_sizes[0] / Nq;   // 1024

    char* w = (char*)d_ws;
    short* protoC  = (short*)w;  w += (size_t)KCLS * D * sizeof(short);  // bf16 [K][D]
    float* mu2part = (float*)w;  w += (size_t)KCLS * 4 * sizeof(float);
    float* S2part  = (float*)w;  w += (size_t)KCLS * 4 * sizeof(float);
    int*   cntA    = (int*)w;    w += KCLS * sizeof(int);

    float* out = (float*)d_out;

    class_stats2<<<KCLS * 4, 256, 0, stream>>>(xs, ys, Ns, D, protoC,
                                               S2part, mu2part, cntA, out);
    main_mfma<<<Nq / QB, 256, 0, stream>>>(xq, yq, ys, pos, protoC, S2part, mu2part,
                                           cntA, xs, Nq, D, 1.0f / (float)Nq, out);
}